// Round 2
// baseline (1146.268 us; speedup 1.0000x reference)
//
#include <hip/hip_runtime.h>
#include <hip/hip_bf16.h>

#define NEGS   0.2f
#define LN_EPS 1e-5f

using bf16 = __hip_bfloat16;

__device__ __forceinline__ float ldv(const float* p, int i){ return p[i]; }
__device__ __forceinline__ float ldv(const bf16*  p, int i){ return __bfloat162float(p[i]); }

// ---------------- dtype detect: flag=1 if float tensors are bf16, 0 if f32 ----------------
__global__ void k_detect(const unsigned short* __restrict__ xr, int* __restrict__ flag){
  int tid = threadIdx.x;                 // 64 threads
  int bad = 0;
  for (int i = tid; i < 256; i += 64){
    unsigned short u = xr[i];
    int ex = (u >> 7) & 0xFF;
    bool sane = ((u & 0x7FFF) == 0) || (ex >= 107 && ex <= 134);  // bf16 ~N(0,1) plausible
    if (!sane) bad++;
  }
  #pragma unroll
  for (int off = 1; off < 64; off <<= 1) bad += __shfl_xor(bad, off);
  if (tid == 0) flag[0] = (bad > 16) ? 0 : 1;
}

// ---------------- input transform: h = relu(x @ w_in + b_in) ----------------
template<typename T>
__global__ __launch_bounds__(256) void k_in(const int* __restrict__ flag, int want,
                                            const T* __restrict__ x, const T* __restrict__ w,
                                            const T* __restrict__ b, float* __restrict__ h, int N){
  if (flag[0] != want) return;
  __shared__ float ws[24*64];
  __shared__ float bs[64];
  __shared__ float xs[4][24];
  int tid = threadIdx.x;
  for (int i = tid; i < 24*64; i += 256) ws[i] = ldv(w, i);
  if (tid < 64) bs[tid] = ldv(b, tid);
  int r = tid >> 6, c = tid & 63;
  int row = blockIdx.x*4 + r;
  if (c < 24 && row < N) xs[r][c] = ldv(x, row*24 + c);
  __syncthreads();
  if (row < N){
    float acc = bs[c];
    #pragma unroll
    for (int k = 0; k < 24; ++k) acc = fmaf(xs[r][k], ws[k*64 + c], acc);
    h[row*64 + c] = fmaxf(acc, 0.f);
  }
}

// ---------------- CSR build (dtype-independent) ----------------
__global__ void k_zero(int* __restrict__ p, int n){
  int i = blockIdx.x*256 + threadIdx.x;
  if (i < n) p[i] = 0;
}

__global__ void k_hist(const int* __restrict__ dst, int* __restrict__ counts, int E){
  int e = blockIdx.x*256 + threadIdx.x;
  if (e < E) atomicAdd(&counts[dst[e]], 1);
}

__global__ __launch_bounds__(256) void k_scan1(const int* __restrict__ counts, int* __restrict__ scanned,
                                               int* __restrict__ bsums, int N){
  __shared__ int s[256];
  int i = blockIdx.x*256 + threadIdx.x;
  int v = (i < N) ? counts[i] : 0;
  s[threadIdx.x] = v;
  __syncthreads();
  for (int off = 1; off < 256; off <<= 1){
    int t = (threadIdx.x >= off) ? s[threadIdx.x - off] : 0;
    __syncthreads();
    s[threadIdx.x] += t;
    __syncthreads();
  }
  if (i < N) scanned[i] = s[threadIdx.x];
  if (threadIdx.x == 255) bsums[blockIdx.x] = s[255];
}

__global__ __launch_bounds__(256) void k_scan2(int* __restrict__ bsums, int NB){
  __shared__ int s[256];
  int v = (threadIdx.x < NB) ? bsums[threadIdx.x] : 0;
  s[threadIdx.x] = v;
  __syncthreads();
  for (int off = 1; off < 256; off <<= 1){
    int t = (threadIdx.x >= off) ? s[threadIdx.x - off] : 0;
    __syncthreads();
    s[threadIdx.x] += t;
    __syncthreads();
  }
  if (threadIdx.x < NB) bsums[threadIdx.x] = s[threadIdx.x] - v;
}

__global__ void k_scan3(const int* __restrict__ scanned, const int* __restrict__ bsums,
                        int* __restrict__ row_ptr, int* __restrict__ cursor, int N){
  int i = blockIdx.x*256 + threadIdx.x;
  if (i < N){
    row_ptr[i+1] = scanned[i] + bsums[blockIdx.x];
    cursor[i] = 0;
    if (i == 0) row_ptr[0] = 0;
  }
}

__global__ void k_scatter(const int* __restrict__ srcA, const int* __restrict__ dstA,
                          const int* __restrict__ row_ptr, int* __restrict__ cursor,
                          int* __restrict__ col, int E){
  int e = blockIdx.x*256 + threadIdx.x;
  if (e < E){
    int d = dstA[e];
    int p = atomicAdd(&cursor[d], 1);
    col[row_ptr[d] + p] = srcA[e];
  }
}

// ---------------- per-layer transforms: xl = h@wl+bl, xr = h@wr+br ----------------
template<typename T>
__global__ __launch_bounds__(256) void k_xfm(const int* __restrict__ flag, int want,
                                             const float* __restrict__ h,
                                             const T* __restrict__ wlg, const T* __restrict__ blg,
                                             const T* __restrict__ wrg, const T* __restrict__ brg,
                                             float* __restrict__ xl, float* __restrict__ xr, int N){
  if (flag[0] != want) return;
  __shared__ float wl[4096];
  __shared__ float wr[4096];
  __shared__ float hs[64*64];
  int tid = threadIdx.x;
  for (int i = tid; i < 4096; i += 256){ wl[i] = ldv(wlg, i); wr[i] = ldv(wrg, i); }
  int row0 = blockIdx.x*64;
  int nrows = min(64, N - row0);
  for (int i = tid; i < nrows*64; i += 256) hs[i] = h[(size_t)row0*64 + i];
  __syncthreads();
  int wave = tid >> 6, c = tid & 63;
  float blv = ldv(blg, c), brv = ldv(brg, c);
  float accl[16], accr[16];
  #pragma unroll
  for (int r = 0; r < 16; ++r){ accl[r] = blv; accr[r] = brv; }
  int rbase = wave*16;
  #pragma unroll 4
  for (int k = 0; k < 64; k += 4){
    float w0 = wl[k*64+c], w1 = wl[(k+1)*64+c], w2 = wl[(k+2)*64+c], w3 = wl[(k+3)*64+c];
    float v0 = wr[k*64+c], v1 = wr[(k+1)*64+c], v2 = wr[(k+2)*64+c], v3 = wr[(k+3)*64+c];
    #pragma unroll
    for (int r = 0; r < 16; ++r){
      float4 hv = *(const float4*)&hs[(rbase + r)*64 + k];
      accl[r] = fmaf(hv.x, w0, fmaf(hv.y, w1, fmaf(hv.z, w2, fmaf(hv.w, w3, accl[r]))));
      accr[r] = fmaf(hv.x, v0, fmaf(hv.y, v1, fmaf(hv.z, v2, fmaf(hv.w, v3, accr[r]))));
    }
  }
  #pragma unroll
  for (int r = 0; r < 16; ++r){
    int row = row0 + rbase + r;
    if (row < N){
      xl[(size_t)row*64 + c] = accl[r];
      xr[(size_t)row*64 + c] = accr[r];
    }
  }
}

// ---------------- fused GATv2 aggregation + residual + LayerNorm (+relu) ----------------
template<typename T>
__global__ __launch_bounds__(256) void k_gat(const int* __restrict__ flag, int want,
                                             const float* __restrict__ xl, const float* __restrict__ xr,
                                             float* __restrict__ h, const int* __restrict__ row_ptr,
                                             const int* __restrict__ col,
                                             const T* __restrict__ att, const T* __restrict__ bg,
                                             const T* __restrict__ lng, const T* __restrict__ lnb,
                                             int N, int do_relu){
  if (flag[0] != want) return;
  int lane = threadIdx.x & 63;
  int node = blockIdx.x*4 + (threadIdx.x >> 6);
  if (node >= N) return;                 // whole wave exits together; no barriers below
  float att_v = ldv(att, lane);
  size_t base = (size_t)node*64 + lane;
  float xr_v = xr[base];
  float xls  = xl[base];
  // self loop initializes online-softmax state
  float t = xls + xr_v; t = t > 0.f ? t : NEGS*t;
  float p = t * att_v;
  p += __shfl_xor(p, 1); p += __shfl_xor(p, 2); p += __shfl_xor(p, 4); p += __shfl_xor(p, 8);
  float m = p, den = 1.f, acc = xls;
  int e0 = row_ptr[node], e1 = row_ptr[node+1];
  for (int e = e0; e < e1; ++e){
    int j = col[e];
    float xlv = xl[(size_t)j*64 + lane];
    float tt = xlv + xr_v; tt = tt > 0.f ? tt : NEGS*tt;
    float s = tt * att_v;
    s += __shfl_xor(s, 1); s += __shfl_xor(s, 2); s += __shfl_xor(s, 4); s += __shfl_xor(s, 8);
    float mn = fmaxf(m, s);
    float f = __expf(m - mn), w = __expf(s - mn);
    den = den*f + w;
    acc = acc*f + w*xlv;
    m = mn;
  }
  float o = acc/den + ldv(bg, lane) + h[base];
  // LayerNorm across the 64 lanes
  float sum = o;
  #pragma unroll
  for (int off = 1; off < 64; off <<= 1) sum += __shfl_xor(sum, off);
  float mean = sum * (1.f/64.f);
  float d = o - mean;
  float vs = d*d;
  #pragma unroll
  for (int off = 1; off < 64; off <<= 1) vs += __shfl_xor(vs, off);
  float var = vs * (1.f/64.f);
  float y = d * rsqrtf(var + LN_EPS) * ldv(lng, lane) + ldv(lnb, lane);
  if (do_relu) y = fmaxf(y, 0.f);
  h[base] = y;
}

// ---------------- gate MLP: gate = relu(h@w_g1+b_g1)@w_g2 + b_g2 ----------------
template<typename T>
__global__ __launch_bounds__(256) void k_gate(const int* __restrict__ flag, int want,
                                              const float* __restrict__ h,
                                              const T* __restrict__ w1, const T* __restrict__ b1,
                                              const T* __restrict__ w2, const T* __restrict__ b2,
                                              float* __restrict__ gate, int N){
  if (flag[0] != want) return;
  __shared__ float w1s[64*32];
  __shared__ float hrow[4][64];
  int tid = threadIdx.x;
  for (int i = tid; i < 2048; i += 256) w1s[i] = ldv(w1, i);
  int wave = tid >> 6, lane = tid & 63;
  int node = blockIdx.x*4 + wave;
  bool valid = node < N;
  hrow[wave][lane] = valid ? h[(size_t)node*64 + lane] : 0.f;
  __syncthreads();
  int j = lane & 31, half = lane >> 5;
  float s = 0.f;
  int k0 = half*32;
  #pragma unroll 8
  for (int k = k0; k < k0 + 32; ++k) s = fmaf(hrow[wave][k], w1s[k*32 + j], s);
  s += __shfl_xor(s, 32);
  float hid = fmaxf(s + ldv(b1, j), 0.f);
  float contrib = (half == 0) ? hid * ldv(w2, j) : 0.f;
  #pragma unroll
  for (int off = 1; off < 64; off <<= 1) contrib += __shfl_xor(contrib, off);
  if (valid && lane == 0) gate[node] = contrib + ldv(b2, 0);
}

// ---------------- per-graph softmax pooling + final GEMM ----------------
template<typename T>
__global__ __launch_bounds__(64) void k_pool(const int* __restrict__ flag, int want,
                                             const float* __restrict__ h, const float* __restrict__ gate,
                                             const int* __restrict__ batch,
                                             const T* __restrict__ w_out, const T* __restrict__ b_out,
                                             void* __restrict__ outp, int N){
  if (flag[0] != want) return;
  int g = blockIdx.x, lane = threadIdx.x;
  int lo = 0, hi = N;
  while (lo < hi){ int mid = (lo + hi) >> 1; if (batch[mid] < g) lo = mid + 1; else hi = mid; }
  int start = lo;
  hi = N;
  while (lo < hi){ int mid = (lo + hi) >> 1; if (batch[mid] < g + 1) lo = mid + 1; else hi = mid; }
  int end = lo;
  float m = -3.4e38f;
  for (int i = start + lane; i < end; i += 64) m = fmaxf(m, gate[i]);
  #pragma unroll
  for (int off = 1; off < 64; off <<= 1) m = fmaxf(m, __shfl_xor(m, off));
  float s = 0.f;
  for (int i = start + lane; i < end; i += 64) s += __expf(gate[i] - m);
  #pragma unroll
  for (int off = 1; off < 64; off <<= 1) s += __shfl_xor(s, off);
  float inv = (s > 0.f) ? 1.f/s : 1.f;
  float acc = 0.f;
  for (int i = start; i < end; ++i){
    float a = __expf(gate[i] - m) * inv;
    acc = fmaf(a, h[(size_t)i*64 + lane], acc);
  }
  __shared__ float emb[64];
  emb[lane] = acc;
  __syncthreads();
  float o2 = ldv(b_out, lane);
  for (int d = 0; d < 64; ++d) o2 = fmaf(emb[d], ldv(w_out, d*64 + lane), o2);
  float y = fmaxf(o2, 0.f);
  if (want == 1) ((bf16*)outp)[g*64 + lane] = __float2bfloat16(y);
  else           ((float*)outp)[g*64 + lane] = y;
}

// ---------------- host-side pipeline (templated on input elem type) ----------------
struct Bufs {
  float *h, *xl, *xr, *gate;
  int *col, *row_ptr;
  int *flag;
};

template<typename T>
static void run_pipeline(void* const* d_in, int want, const Bufs& B, const int* batch,
                         void* d_out, int N, int G, hipStream_t stream){
  const T* x     = (const T*)d_in[0];
  const T* w_in  = (const T*)d_in[3];
  const T* b_in  = (const T*)d_in[4];
  const T* w_l   = (const T*)d_in[5];
  const T* b_l   = (const T*)d_in[6];
  const T* w_r   = (const T*)d_in[7];
  const T* b_r   = (const T*)d_in[8];
  const T* att   = (const T*)d_in[9];
  const T* b_gat = (const T*)d_in[10];
  const T* ln_g  = (const T*)d_in[11];
  const T* ln_b  = (const T*)d_in[12];
  const T* w_g1  = (const T*)d_in[13];
  const T* b_g1  = (const T*)d_in[14];
  const T* w_g2  = (const T*)d_in[15];
  const T* b_g2  = (const T*)d_in[16];
  const T* w_out = (const T*)d_in[17];
  const T* b_out = (const T*)d_in[18];

  k_in<T><<<(N + 3)/4, 256, 0, stream>>>(B.flag, want, x, w_in, b_in, B.h, N);
  for (int i = 0; i < 3; ++i){
    k_xfm<T><<<(N + 63)/64, 256, 0, stream>>>(B.flag, want, B.h,
                                              w_l + i*4096, b_l + i*64, w_r + i*4096, b_r + i*64,
                                              B.xl, B.xr, N);
    k_gat<T><<<(N + 3)/4, 256, 0, stream>>>(B.flag, want, B.xl, B.xr, B.h, B.row_ptr, B.col,
                                            att + i*64, b_gat + i*64, ln_g + i*64, ln_b + i*64,
                                            N, i < 2 ? 1 : 0);
  }
  k_gate<T><<<(N + 3)/4, 256, 0, stream>>>(B.flag, want, B.h, w_g1, b_g1, w_g2, b_g2, B.gate, N);
  k_pool<T><<<G, 64, 0, stream>>>(B.flag, want, B.h, B.gate, batch, w_out, b_out, d_out, N);
}

extern "C" void kernel_launch(void* const* d_in, const int* in_sizes, int n_in,
                              void* d_out, int out_size, void* d_ws, size_t ws_size,
                              hipStream_t stream) {
  const int N = in_sizes[0] / 24;
  const int E = in_sizes[1] / 2;
  const int G = out_size / 64;

  const int* edge  = (const int*)d_in[1];
  const int* batch = (const int*)d_in[2];

  char* wp = (char*)d_ws;
  auto alloc = [&](size_t bytes) -> char* {
    char* p = wp; wp += (bytes + 255) & ~(size_t)255; return p;
  };
  Bufs B;
  B.flag    = (int*)  alloc(256);
  B.h       = (float*)alloc((size_t)N*64*sizeof(float));
  B.xl      = (float*)alloc((size_t)N*64*sizeof(float));
  B.xr      = (float*)alloc((size_t)N*64*sizeof(float));
  B.col     = (int*)  alloc((size_t)E*sizeof(int));
  B.row_ptr = (int*)  alloc((size_t)(N+1)*sizeof(int));
  int* counts  = (int*)alloc((size_t)N*sizeof(int));
  int* scanned = (int*)alloc((size_t)N*sizeof(int));
  int* cursor  = (int*)alloc((size_t)N*sizeof(int));
  int* bsums   = (int*)alloc(256*sizeof(int));
  B.gate    = (float*)alloc((size_t)N*sizeof(float));

  const int* srcA = edge;
  const int* dstA = edge + E;
  const int NB = (N + 255) / 256;

  k_detect<<<1, 64, 0, stream>>>((const unsigned short*)d_in[0], B.flag);

  // CSR build (dtype-independent)
  k_zero<<<NB, 256, 0, stream>>>(counts, N);
  k_hist<<<(E + 255)/256, 256, 0, stream>>>(dstA, counts, E);
  k_scan1<<<NB, 256, 0, stream>>>(counts, scanned, bsums, N);
  k_scan2<<<1, 256, 0, stream>>>(bsums, NB);
  k_scan3<<<NB, 256, 0, stream>>>(scanned, bsums, B.row_ptr, cursor, N);
  k_scatter<<<(E + 255)/256, 256, 0, stream>>>(srcA, dstA, B.row_ptr, cursor, B.col, E);

  // Enqueue both dtype pipelines; the flag gates which one does work.
  run_pipeline<bf16 >(d_in, 1, B, batch, d_out, N, G, stream);
  run_pipeline<float>(d_in, 0, B, batch, d_out, N, G, stream);
}